// Round 2
// baseline (181.831 us; speedup 1.0000x reference)
//
#include <hip/hip_runtime.h>
#include <stdint.h>

#define NPTS   131072
#define DEMB   512
#define NCL    512
#define BM     64
#define BK     64
#define NCHUNK (DEMB / BK)          // 8
#define NTHREADS 512
#define NBLK   (NPTS / BM)          // 2048

typedef __attribute__((ext_vector_type(4))) float f32x4;
typedef __attribute__((ext_vector_type(8))) short short8;

// ---- workspace layout (bytes) ----
// [0, 512KB)  : bf16 centroid fragments, laid out per (chunk, wave, kk, n, lane)
//               so each wave's MFMA B-fragment loads are contiguous 1KB reads.
// [512KB,+2KB): c2[k] = ||c_k||^2 (f32)
// [514KB,+8KB): per-block partial sums (f32)
#define WS_CB   0u
#define WS_C2   (512u * 1024u)
#define WS_PART (WS_C2 + 2048u)

static __device__ __forceinline__ unsigned short f2bf(float f) {
  union { float f; uint32_t u; } c{f};
  uint32_t r = c.u + 0x7FFFu + ((c.u >> 16) & 1u);   // round-to-nearest-even
  return (unsigned short)(r >> 16);
}

// ---------- prep: c2 + bf16 centroid fragments in register-load layout ----------
// For chunk ch, wave w, kk, n: lane (lhi*16+l15) must receive the 16B holding
// cluster (w*64 + n*16 + l15), d = ch*64 + (kk*4+lhi)*8 .. +8.
__global__ __launch_bounds__(128) void prep_kernel(const float* __restrict__ cent,
                                                   uint8_t* __restrict__ ws) {
  const int k = blockIdx.x;
  const int t = threadIdx.x;
  float4 v = ((const float4*)(cent + (size_t)k * DEMB))[t];
  float sq = v.x * v.x + v.y * v.y + v.z * v.z + v.w * v.w;
#pragma unroll
  for (int m = 1; m < 64; m <<= 1) sq += __shfl_xor(sq, m, 64);
  __shared__ float red[2];
  if ((t & 63) == 0) red[t >> 6] = sq;
  __syncthreads();
  if (t == 0) ((float*)(ws + WS_C2))[k] = red[0] + red[1];

  ushort4 b;
  b.x = f2bf(v.x); b.y = f2bf(v.y); b.z = f2bf(v.z); b.w = f2bf(v.w);
  const int d = t * 4;
  const int ch = d >> 6;
  const int dd = d & 63;
  const int slot = dd >> 3;            // 0..7
  const int kk = slot >> 2;            // 0..1
  const int lhi = slot & 3;            // 0..3
  const int w = k >> 6;
  const int kc = k & 63;
  const int n = kc >> 4;
  const int l15 = kc & 15;
  const int lane = lhi * 16 + l15;
  const uint32_t off =
      ((((uint32_t)(ch * 8 + w) * 2u + (uint32_t)kk) * 4u + (uint32_t)n) * 64u +
       (uint32_t)lane) * 16u + (uint32_t)(dd & 7) * 2u;
  *(ushort4*)(ws + WS_CB + off) = b;
}

// ---------- fused GEMM + softmin epilogue ----------
__global__ __launch_bounds__(NTHREADS, 3) void main_kernel(
    const float* __restrict__ emb, const uint8_t* __restrict__ ws,
    const float* __restrict__ alphap) {
  __shared__ uint8_t xsm[2][8192];     // double-buffered x tile [64 rows][64 d] bf16, XOR-swizzled
  __shared__ float redmin[512];
  __shared__ float redse[512];
  __shared__ float redsge[512];
  __shared__ float gmin[64];
  __shared__ float x2s[64];
  __shared__ float vals[64];

  const int t = threadIdx.x;
  const int w = t >> 6;                // wave 0..7 -> clusters [64w, 64w+64)
  const int l = t & 63;
  const int l15 = l & 15;
  const int lhi = l >> 4;              // 0..3
  const int bid = blockIdx.x;
  const size_t row0 = (size_t)bid * BM;

  const float alpha = alphap[0];
  const float* c2g = (const float*)(ws + WS_C2);
  float* partials = (float*)(ws + WS_PART);

  float c2r[4];
#pragma unroll
  for (int n = 0; n < 4; ++n) c2r[n] = c2g[w * 64 + n * 16 + l15];

  f32x4 acc[4][4];
#pragma unroll
  for (int m = 0; m < 4; ++m)
#pragma unroll
    for (int n = 0; n < 4; ++n) acc[m][n] = (f32x4){0.f, 0.f, 0.f, 0.f};

  // x staging thread mapping: thread handles (row r0, f32x4 col c0) and (r0+32, c0)
  const int r0 = t >> 4;
  const int c0 = t & 15;
  const int r1 = r0 + 32;
  const int slotc = c0 >> 1;
  const int withn = (c0 & 1) * 8;
  const uint32_t xoff0 = (uint32_t)r0 * 128u + (uint32_t)(((slotc ^ (r0 & 7)) << 4) + withn);
  const uint32_t xoff1 = (uint32_t)r1 * 128u + (uint32_t)(((slotc ^ (r1 & 7)) << 4) + withn);
  const float* xg0 = emb + (row0 + r0) * DEMB + c0 * 4;
  const float* xg1 = emb + (row0 + r1) * DEMB + c0 * 4;

  float x2a0 = 0.f, x2a1 = 0.f;

  // ---- prologue: stage chunk 0 into buffer 0 ----
  {
    float4 v0 = *(const float4*)(xg0);
    float4 v1 = *(const float4*)(xg1);
    x2a0 += v0.x * v0.x + v0.y * v0.y + v0.z * v0.z + v0.w * v0.w;
    x2a1 += v1.x * v1.x + v1.y * v1.y + v1.z * v1.z + v1.w * v1.w;
    ushort4 b0, b1;
    b0.x = f2bf(v0.x); b0.y = f2bf(v0.y); b0.z = f2bf(v0.z); b0.w = f2bf(v0.w);
    b1.x = f2bf(v1.x); b1.y = f2bf(v1.y); b1.z = f2bf(v1.z); b1.w = f2bf(v1.w);
    *(ushort4*)(&xsm[0][0] + xoff0) = b0;
    *(ushort4*)(&xsm[0][0] + xoff1) = b1;
  }
  __syncthreads();

  const uint8_t* wb = ws + WS_CB;
  // per-wave fragment base: lane l's 16B within (ch, w, kk, n) group
  const uint8_t* fb = wb + ((uint32_t)(w * 2 * 4 * 64) + (uint32_t)l) * 16u;

#pragma unroll
  for (int ch = 0; ch < NCHUNK; ++ch) {
    // issue next x chunk's HBM loads early (latency hides under MFMAs)
    float4 v0, v1;
    if (ch + 1 < NCHUNK) {
      v0 = *(const float4*)(xg0 + (ch + 1) * 64);
      v1 = *(const float4*)(xg1 + (ch + 1) * 64);
    }

    const uint8_t* xb = &xsm[ch & 1][0];
    const uint32_t abase = (uint32_t)l15 * 128u;
#pragma unroll
    for (int kk = 0; kk < 2; ++kk) {
      const int slot = kk * 4 + lhi;
      short8 af[4], bfr[4];
      const uint32_t aoff = abase + (uint32_t)((slot ^ (l15 & 7)) << 4);
#pragma unroll
      for (int m = 0; m < 4; ++m)
        af[m] = *(const short8*)(xb + aoff + (uint32_t)m * 2048u);
#pragma unroll
      for (int n = 0; n < 4; ++n)
        bfr[n] = *(const short8*)(fb + ((uint32_t)(ch * 8 + 0) * 8u + (uint32_t)kk * 4u + (uint32_t)n) * 1024u);
#pragma unroll
      for (int m = 0; m < 4; ++m)
#pragma unroll
        for (int n = 0; n < 4; ++n)
          acc[m][n] = __builtin_amdgcn_mfma_f32_16x16x32_bf16(af[m], bfr[n], acc[m][n], 0, 0, 0);
    }

    if (ch + 1 < NCHUNK) {
      x2a0 += v0.x * v0.x + v0.y * v0.y + v0.z * v0.z + v0.w * v0.w;
      x2a1 += v1.x * v1.x + v1.y * v1.y + v1.z * v1.z + v1.w * v1.w;
      ushort4 b0, b1;
      b0.x = f2bf(v0.x); b0.y = f2bf(v0.y); b0.z = f2bf(v0.z); b0.w = f2bf(v0.w);
      b1.x = f2bf(v1.x); b1.y = f2bf(v1.y); b1.z = f2bf(v1.z); b1.w = f2bf(v1.w);
      uint8_t* xn = &xsm[(ch + 1) & 1][0];
      *(ushort4*)(xn + xoff0) = b0;
      *(ushort4*)(xn + xoff1) = b1;
    }
    __syncthreads();
  }

  // ---- epilogue: g = c2 - 2*s ; val_row = min + sum((g-M)e)/sum(e) + x2 ----
#pragma unroll
  for (int m = 1; m < 16; m <<= 1) {
    x2a0 += __shfl_xor(x2a0, m, 64);
    x2a1 += __shfl_xor(x2a1, m, 64);
  }
  if ((t & 15) == 0) {
    x2s[t >> 4] = x2a0;
    x2s[32 + (t >> 4)] = x2a1;
  }

  float rmin[4][4];
#pragma unroll
  for (int m = 0; m < 4; ++m)
#pragma unroll
    for (int i = 0; i < 4; ++i) {
      float mn = c2r[0] - 2.f * acc[m][0][i];
#pragma unroll
      for (int n = 1; n < 4; ++n) mn = fminf(mn, c2r[n] - 2.f * acc[m][n][i]);
      rmin[m][i] = mn;
    }
#pragma unroll
  for (int msk = 1; msk < 16; msk <<= 1)
#pragma unroll
    for (int m = 0; m < 4; ++m)
#pragma unroll
      for (int i = 0; i < 4; ++i)
        rmin[m][i] = fminf(rmin[m][i], __shfl_xor(rmin[m][i], msk, 64));
  if (l15 == 0) {
#pragma unroll
    for (int m = 0; m < 4; ++m)
#pragma unroll
      for (int i = 0; i < 4; ++i)
        redmin[w * 64 + m * 16 + lhi * 4 + i] = rmin[m][i];
  }
  __syncthreads();
  if (t < 64) {
    float mn = redmin[t];
#pragma unroll
    for (int w2 = 1; w2 < 8; ++w2) mn = fminf(mn, redmin[w2 * 64 + t]);
    gmin[t] = mn;
  }
  __syncthreads();
#pragma unroll
  for (int m = 0; m < 4; ++m) {
#pragma unroll
    for (int i = 0; i < 4; ++i) {
      const int row = m * 16 + lhi * 4 + i;
      const float M = gmin[row];
      float se = 0.f, sge = 0.f;
#pragma unroll
      for (int n = 0; n < 4; ++n) {
        const float g = c2r[n] - 2.f * acc[m][n][i];
        const float gm = g - M;
        const float e = __expf(-alpha * gm);
        se += e;
        sge += gm * e;
      }
#pragma unroll
      for (int msk = 1; msk < 16; msk <<= 1) {
        se += __shfl_xor(se, msk, 64);
        sge += __shfl_xor(sge, msk, 64);
      }
      if (l15 == 0) {
        redse[w * 64 + row] = se;
        redsge[w * 64 + row] = sge;
      }
    }
  }
  __syncthreads();
  if (t < 64) {
    float Se = 0.f, Sge = 0.f;
#pragma unroll
    for (int w2 = 0; w2 < 8; ++w2) {
      Se += redse[w2 * 64 + t];
      Sge += redsge[w2 * 64 + t];
    }
    vals[t] = gmin[t] + Sge / Se + x2s[t];
  }
  __syncthreads();
  if (t < 64) {
    float v = vals[t];
#pragma unroll
    for (int msk = 1; msk < 64; msk <<= 1) v += __shfl_xor(v, msk, 64);
    if (t == 0) partials[bid] = v;
  }
}

// ---------- final deterministic reduction ----------
__global__ __launch_bounds__(256) void final_kernel(const uint8_t* __restrict__ ws,
                                                    const float* __restrict__ lambdp,
                                                    float* __restrict__ out) {
  const float* partials = (const float*)(ws + WS_PART);
  const int t = threadIdx.x;
  float s = 0.f;
  for (int i = t; i < NBLK; i += 256) s += partials[i];
#pragma unroll
  for (int msk = 1; msk < 64; msk <<= 1) s += __shfl_xor(s, msk, 64);
  __shared__ float red[4];
  if ((t & 63) == 0) red[t >> 6] = s;
  __syncthreads();
  if (t == 0)
    out[0] = lambdp[0] * (red[0] + red[1] + red[2] + red[3]) * (1.0f / (float)NPTS);
}

extern "C" void kernel_launch(void* const* d_in, const int* in_sizes, int n_in,
                              void* d_out, int out_size, void* d_ws, size_t ws_size,
                              hipStream_t stream) {
  const float* emb = (const float*)d_in[0];
  const float* cent = (const float*)d_in[1];
  const float* alphap = (const float*)d_in[2];
  const float* lambdp = (const float*)d_in[3];
  float* out = (float*)d_out;
  uint8_t* ws = (uint8_t*)d_ws;

  prep_kernel<<<NCL, 128, 0, stream>>>(cent, ws);
  main_kernel<<<NBLK, NTHREADS, 0, stream>>>(emb, ws, alphap);
  final_kernel<<<1, 256, 0, stream>>>(ws, lambdp, out);
}

// Round 3
// 158.871 us; speedup vs baseline: 1.1445x; 1.1445x over previous
//
#include <hip/hip_runtime.h>
#include <stdint.h>

#define NPTS   131072
#define DEMB   512
#define NCL    512
#define BM     64
#define BK     64
#define NCHUNK 8
#define NTHREADS 512
#define NBLK   (NPTS / BM)          // 2048

typedef __attribute__((ext_vector_type(4))) float f32x4;
typedef __attribute__((ext_vector_type(8))) short short8;

// ---- workspace layout (bytes) ----
// [0, 512KB)  : bf16 centroids, 8 chunk-images of 64KB, pre-swizzled LDS layout
// [512KB,+2KB): c2[k] = ||c_k||^2 (f32)
// [514KB,+8KB): per-block partial sums (f32)
#define WS_CB   0u
#define WS_C2   (512u * 1024u)
#define WS_PART (WS_C2 + 2048u)

static __device__ __forceinline__ unsigned short f2bf(float f) {
  union { float f; uint32_t u; } c{f};
  uint32_t r = c.u + 0x7FFFu + ((c.u >> 16) & 1u);   // round-to-nearest-even
  return (unsigned short)(r >> 16);
}

typedef const __attribute__((address_space(1))) void gvoid;
typedef __attribute__((address_space(3))) void svoid;
static __device__ __forceinline__ void llds16(const void* g, void* s) {
  __builtin_amdgcn_global_load_lds((gvoid*)g, (svoid*)s, 16, 0, 0);
}

// ---------- prep: c2 + bf16-convert centroids into pre-swizzled chunk images ----------
__global__ __launch_bounds__(128) void prep_kernel(const float* __restrict__ cent,
                                                   uint8_t* __restrict__ ws) {
  const int k = blockIdx.x;
  const int t = threadIdx.x;
  float4 v = ((const float4*)(cent + (size_t)k * DEMB))[t];
  float sq = v.x * v.x + v.y * v.y + v.z * v.z + v.w * v.w;
#pragma unroll
  for (int m = 1; m < 64; m <<= 1) sq += __shfl_xor(sq, m, 64);
  __shared__ float red[2];
  if ((t & 63) == 0) red[t >> 6] = sq;
  __syncthreads();
  if (t == 0) ((float*)(ws + WS_C2))[k] = red[0] + red[1];

  ushort4 b;
  b.x = f2bf(v.x); b.y = f2bf(v.y); b.z = f2bf(v.z); b.w = f2bf(v.w);
  const int d = t * 4;
  const int chunk = d >> 6;
  const int dd = d & 63;
  const int slot = dd >> 3;            // 16B slot within 128B row
  const int within = (dd & 7) * 2;
  const uint32_t off = (uint32_t)chunk * 65536u + (uint32_t)k * 128u +
                       (uint32_t)(((slot ^ (k & 7)) << 4) + within);
  *(ushort4*)(ws + WS_CB + off) = b;
}

// ---------- fused GEMM + softmin epilogue, counted-vmcnt pipeline ----------
// LDS map (dynamic, 147456 B):
//   B0 @ 0       (65536)   B1 @ 65536 (65536)
//   A0 @ 131072  (8192)    A1 @ 139264 (8192)
//   epilogue aliases B0: redmin@0 redse@2048 redsge@4096 gmin@6144 x2s@6400 vals@6656
__global__ __launch_bounds__(NTHREADS, 2) void main_kernel(
    const float* __restrict__ emb, const uint8_t* __restrict__ ws,
    const float* __restrict__ alphap) {
  extern __shared__ uint8_t smem[];

  const int t = threadIdx.x;
  const int w = t >> 6;                // wave 0..7 -> clusters [64w, 64w+64)
  const int l = t & 63;
  const int l15 = l & 15;
  const int lhi = l >> 4;              // 0..3
  const int bid = blockIdx.x;
  const size_t row0 = (size_t)bid * BM;

  const float alpha = alphap[0];
  const float* c2g = (const float*)(ws + WS_C2);
  float* partials = (float*)(ws + WS_PART);

  float c2r[4];
#pragma unroll
  for (int n = 0; n < 4; ++n) c2r[n] = c2g[w * 64 + n * 16 + l15];

  f32x4 acc[4][4];
#pragma unroll
  for (int m = 0; m < 4; ++m)
#pragma unroll
    for (int n = 0; n < 4; ++n) acc[m][n] = (f32x4){0.f, 0.f, 0.f, 0.f};

  // x staging thread mapping: thread handles (row r0, float4 col c0) and (r0+32, c0)
  const int r0 = t >> 4;
  const int c0 = t & 15;
  const int r1 = r0 + 32;
  const int slotc = c0 >> 1;
  const int withn = (c0 & 1) * 8;
  const uint32_t xoff0 = (uint32_t)r0 * 128u + (uint32_t)(((slotc ^ (r0 & 7)) << 4) + withn);
  const uint32_t xoff1 = (uint32_t)r1 * 128u + (uint32_t)(((slotc ^ (r1 & 7)) << 4) + withn);
  const float* xg0 = emb + (row0 + r0) * DEMB + c0 * 4;
  const float* xg1 = emb + (row0 + r1) * DEMB + c0 * 4;

  float x2a0 = 0.f, x2a1 = 0.f;

  const uint8_t* wsb = ws + WS_CB + (uint32_t)w * 8192u + (uint32_t)l * 16u;

  // ---- prologue ----
  float4 pa0 = *(const float4*)(xg0);            // emb[0]
  float4 pa1 = *(const float4*)(xg1);
  float4 pb0 = *(const float4*)(xg0 + 64);       // emb[1]
  float4 pb1 = *(const float4*)(xg1 + 64);
  {
    // issue B[0] -> B-buf 0
    const uint8_t* src = wsb;                    // chunk 0
    uint8_t* dst = smem + w * 8192;
#pragma unroll
    for (int i = 0; i < 8; ++i) llds16(src + i * 1024, dst + i * 1024);
  }
  {
    // write A[0] -> A-buf 0 (compiler inserts its own wait for pa)
    x2a0 += pa0.x * pa0.x + pa0.y * pa0.y + pa0.z * pa0.z + pa0.w * pa0.w;
    x2a1 += pa1.x * pa1.x + pa1.y * pa1.y + pa1.z * pa1.z + pa1.w * pa1.w;
    ushort4 b0, b1;
    b0.x = f2bf(pa0.x); b0.y = f2bf(pa0.y); b0.z = f2bf(pa0.z); b0.w = f2bf(pa0.w);
    b1.x = f2bf(pa1.x); b1.y = f2bf(pa1.y); b1.z = f2bf(pa1.z); b1.w = f2bf(pa1.w);
    *(ushort4*)(smem + 131072 + xoff0) = b0;
    *(ushort4*)(smem + 131072 + xoff1) = b1;
  }
  asm volatile("s_waitcnt lgkmcnt(0)" ::: "memory");

#pragma unroll
  for (int ch = 0; ch < NCHUNK; ++ch) {
    // issue B[ch+1] into the other B-buf, then counted wait: the 8 newest
    // outstanding are B[ch+1]; vmcnt(8) => B[ch] (and older emb) landed.
    if (ch + 1 < NCHUNK) {
      const uint8_t* src = wsb + (uint32_t)(ch + 1) * 65536u;
      uint8_t* dst = smem + (((ch + 1) & 1) << 16) + w * 8192;
#pragma unroll
      for (int i = 0; i < 8; ++i) llds16(src + i * 1024, dst + i * 1024);
      asm volatile("s_waitcnt vmcnt(8)" ::: "memory");
    } else {
      asm volatile("s_waitcnt vmcnt(0)" ::: "memory");
    }
    __builtin_amdgcn_s_barrier();

    // depth-2 emb prefetch: load emb[ch+2] into pair (ch&1)==... pair index (ch+2)&1
    if (ch + 2 < NCHUNK) {
      if (ch & 1) {
        pb0 = *(const float4*)(xg0 + (ch + 2) * 64);
        pb1 = *(const float4*)(xg1 + (ch + 2) * 64);
      } else {
        pa0 = *(const float4*)(xg0 + (ch + 2) * 64);
        pa1 = *(const float4*)(xg1 + (ch + 2) * 64);
      }
    }

    // fragment reads + MFMA on chunk ch
    const uint8_t* xb = smem + 131072 + ((ch & 1) << 13);
    const uint8_t* bb = smem + ((ch & 1) << 16) + w * 8192;
    __builtin_amdgcn_s_setprio(1);
#pragma unroll
    for (int kk = 0; kk < 2; ++kk) {
      const int slot = kk * 4 + lhi;
      const uint32_t fo = (uint32_t)l15 * 128u + (uint32_t)((slot ^ (l15 & 7)) << 4);
      short8 af[4], bfr[4];
#pragma unroll
      for (int m = 0; m < 4; ++m) af[m] = *(const short8*)(xb + fo + (uint32_t)m * 2048u);
#pragma unroll
      for (int n = 0; n < 4; ++n) bfr[n] = *(const short8*)(bb + fo + (uint32_t)n * 2048u);
#pragma unroll
      for (int m = 0; m < 4; ++m)
#pragma unroll
        for (int n = 0; n < 4; ++n)
          acc[m][n] = __builtin_amdgcn_mfma_f32_16x16x32_bf16(af[m], bfr[n], acc[m][n], 0, 0, 0);
    }
    __builtin_amdgcn_s_setprio(0);

    // stage A[ch+1] from emb[ch+1] regs (pair (ch+1)&1)
    if (ch + 1 < NCHUNK) {
      float4 q0 = (ch & 1) ? pa0 : pb0;
      float4 q1 = (ch & 1) ? pa1 : pb1;
      x2a0 += q0.x * q0.x + q0.y * q0.y + q0.z * q0.z + q0.w * q0.w;
      x2a1 += q1.x * q1.x + q1.y * q1.y + q1.z * q1.z + q1.w * q1.w;
      ushort4 b0, b1;
      b0.x = f2bf(q0.x); b0.y = f2bf(q0.y); b0.z = f2bf(q0.z); b0.w = f2bf(q0.w);
      b1.x = f2bf(q1.x); b1.y = f2bf(q1.y); b1.z = f2bf(q1.z); b1.w = f2bf(q1.w);
      uint8_t* an = smem + 131072 + (((ch + 1) & 1) << 13);
      *(ushort4*)(an + xoff0) = b0;
      *(ushort4*)(an + xoff1) = b1;
    }
    asm volatile("s_waitcnt lgkmcnt(0)" ::: "memory");
  }

  // ---- epilogue (aliases B0 region; B0 last read at ch=6, separated by ch=7 barrier) ----
  float* redmin = (float*)(smem + 0);
  float* redse  = (float*)(smem + 2048);
  float* redsge = (float*)(smem + 4096);
  float* gmin   = (float*)(smem + 6144);
  float* x2s    = (float*)(smem + 6400);
  float* vals   = (float*)(smem + 6656);

#pragma unroll
  for (int m = 1; m < 16; m <<= 1) {
    x2a0 += __shfl_xor(x2a0, m, 64);
    x2a1 += __shfl_xor(x2a1, m, 64);
  }
  if ((t & 15) == 0) {
    x2s[t >> 4] = x2a0;
    x2s[32 + (t >> 4)] = x2a1;
  }

  float rmin[4][4];
#pragma unroll
  for (int m = 0; m < 4; ++m)
#pragma unroll
    for (int i = 0; i < 4; ++i) {
      float mn = c2r[0] - 2.f * acc[m][0][i];
#pragma unroll
      for (int n = 1; n < 4; ++n) mn = fminf(mn, c2r[n] - 2.f * acc[m][n][i]);
      rmin[m][i] = mn;
    }
#pragma unroll
  for (int msk = 1; msk < 16; msk <<= 1)
#pragma unroll
    for (int m = 0; m < 4; ++m)
#pragma unroll
      for (int i = 0; i < 4; ++i)
        rmin[m][i] = fminf(rmin[m][i], __shfl_xor(rmin[m][i], msk, 64));
  if (l15 == 0) {
#pragma unroll
    for (int m = 0; m < 4; ++m)
#pragma unroll
      for (int i = 0; i < 4; ++i)
        redmin[w * 64 + m * 16 + lhi * 4 + i] = rmin[m][i];
  }
  __syncthreads();
  if (t < 64) {
    float mn = redmin[t];
#pragma unroll
    for (int w2 = 1; w2 < 8; ++w2) mn = fminf(mn, redmin[w2 * 64 + t]);
    gmin[t] = mn;
  }
  __syncthreads();
#pragma unroll
  for (int m = 0; m < 4; ++m) {
#pragma unroll
    for (int i = 0; i < 4; ++i) {
      const int row = m * 16 + lhi * 4 + i;
      const float M = gmin[row];
      float se = 0.f, sge = 0.f;
#pragma unroll
      for (int n = 0; n < 4; ++n) {
        const float g = c2r[n] - 2.f * acc[m][n][i];
        const float gm = g - M;
        const float e = __expf(-alpha * gm);
        se += e;
        sge += gm * e;
      }
#pragma unroll
      for (int msk = 1; msk < 16; msk <<= 1) {
        se += __shfl_xor(se, msk, 64);
        sge += __shfl_xor(sge, msk, 64);
      }
      if (l15 == 0) {
        redse[w * 64 + row] = se;
        redsge[w * 64 + row] = sge;
      }
    }
  }
  __syncthreads();
  if (t < 64) {
    float Se = 0.f, Sge = 0.f;
#pragma unroll
    for (int w2 = 0; w2 < 8; ++w2) {
      Se += redse[w2 * 64 + t];
      Sge += redsge[w2 * 64 + t];
    }
    vals[t] = gmin[t] + Sge / Se + x2s[t];
  }
  __syncthreads();
  if (t < 64) {
    float v = vals[t];
#pragma unroll
    for (int msk = 1; msk < 64; msk <<= 1) v += __shfl_xor(v, msk, 64);
    if (t == 0) partials[bid] = v;
  }
}

// ---------- final deterministic reduction ----------
__global__ __launch_bounds__(256) void final_kernel(const uint8_t* __restrict__ ws,
                                                    const float* __restrict__ lambdp,
                                                    float* __restrict__ out) {
  const float* partials = (const float*)(ws + WS_PART);
  const int t = threadIdx.x;
  float s = 0.f;
  for (int i = t; i < NBLK; i += 256) s += partials[i];
#pragma unroll
  for (int msk = 1; msk < 64; msk <<= 1) s += __shfl_xor(s, msk, 64);
  __shared__ float red[4];
  if ((t & 63) == 0) red[t >> 6] = s;
  __syncthreads();
  if (t == 0)
    out[0] = lambdp[0] * (red[0] + red[1] + red[2] + red[3]) * (1.0f / (float)NPTS);
}

extern "C" void kernel_launch(void* const* d_in, const int* in_sizes, int n_in,
                              void* d_out, int out_size, void* d_ws, size_t ws_size,
                              hipStream_t stream) {
  const float* emb = (const float*)d_in[0];
  const float* cent = (const float*)d_in[1];
  const float* alphap = (const float*)d_in[2];
  const float* lambdp = (const float*)d_in[3];
  float* out = (float*)d_out;
  uint8_t* ws = (uint8_t*)d_ws;

  (void)hipFuncSetAttribute((const void*)main_kernel,
                            hipFuncAttributeMaxDynamicSharedMemorySize, 147456);

  prep_kernel<<<NCL, 128, 0, stream>>>(cent, ws);
  main_kernel<<<NBLK, NTHREADS, 147456, stream>>>(emb, ws, alphap);
  final_kernel<<<1, 256, 0, stream>>>(ws, lambdp, out);
}

// Round 4
// 144.414 us; speedup vs baseline: 1.2591x; 1.1001x over previous
//
#include <hip/hip_runtime.h>
#include <stdint.h>

#define NPTS   131072
#define DEMB   512
#define NCL    512
#define BM     64
#define NCHUNK 8
#define NTHREADS 512
#define NBLK   (NPTS / BM)          // 2048

typedef __attribute__((ext_vector_type(4))) float f32x4;
typedef __attribute__((ext_vector_type(8))) short short8;

// ---- workspace layout (bytes) ----
// [0, 512KB)  : bf16 centroid fragments, laid out per (chunk, wave, kk, n, lane)
//               so each wave's MFMA B-fragment load is a contiguous 1KB read.
// [512KB,+2KB): c2[k] = ||c_k||^2 (f32)
// [514KB,+8KB): per-block partial sums (f32)
#define WS_CB   0u
#define WS_C2   (512u * 1024u)
#define WS_PART (WS_C2 + 2048u)

static __device__ __forceinline__ unsigned short f2bf(float f) {
  union { float f; uint32_t u; } c{f};
  uint32_t r = c.u + 0x7FFFu + ((c.u >> 16) & 1u);   // round-to-nearest-even
  return (unsigned short)(r >> 16);
}

// ---------- prep: c2 + bf16 centroid fragments in register-load layout ----------
// For chunk ch, wave w, kk, n: lane (lhi*16+l15) receives the 16B holding
// cluster (w*64 + n*16 + l15), d = ch*64 + (kk*4+lhi)*8 .. +8.
__global__ __launch_bounds__(128) void prep_kernel(const float* __restrict__ cent,
                                                   uint8_t* __restrict__ ws) {
  const int k = blockIdx.x;
  const int t = threadIdx.x;
  float4 v = ((const float4*)(cent + (size_t)k * DEMB))[t];
  float sq = v.x * v.x + v.y * v.y + v.z * v.z + v.w * v.w;
#pragma unroll
  for (int m = 1; m < 64; m <<= 1) sq += __shfl_xor(sq, m, 64);
  __shared__ float red[2];
  if ((t & 63) == 0) red[t >> 6] = sq;
  __syncthreads();
  if (t == 0) ((float*)(ws + WS_C2))[k] = red[0] + red[1];

  ushort4 b;
  b.x = f2bf(v.x); b.y = f2bf(v.y); b.z = f2bf(v.z); b.w = f2bf(v.w);
  const int d = t * 4;
  const int ch = d >> 6;
  const int dd = d & 63;
  const int slot = dd >> 3;            // 0..7
  const int kk = slot >> 2;            // 0..1
  const int lhi = slot & 3;            // 0..3
  const int w = k >> 6;
  const int kc = k & 63;
  const int n = kc >> 4;
  const int l15 = kc & 15;
  const int lane = lhi * 16 + l15;
  const uint32_t off =
      ((((uint32_t)(ch * 8 + w) * 2u + (uint32_t)kk) * 4u + (uint32_t)n) * 64u +
       (uint32_t)lane) * 16u + (uint32_t)(dd & 7) * 2u;
  *(ushort4*)(ws + WS_CB + off) = b;
}

// ---------- fused GEMM + softmin epilogue: B in regs, A dbuf in LDS ----------
__global__ __launch_bounds__(NTHREADS, 2) void main_kernel(
    const float* __restrict__ emb, const uint8_t* __restrict__ ws,
    const float* __restrict__ alphap) {
  __shared__ uint8_t Ab[2][8192];      // A tile dbuf [64 rows][64 d] bf16, XOR-swizzled
  __shared__ float redmin[512];
  __shared__ float redse[512];
  __shared__ float redsge[512];
  __shared__ float gmin[64];
  __shared__ float x2s[64];
  __shared__ float vals[64];

  const int t = threadIdx.x;
  const int w = t >> 6;                // wave 0..7 -> clusters [64w, 64w+64)
  const int l = t & 63;
  const int l15 = l & 15;
  const int lhi = l >> 4;              // 0..3
  const int bid = blockIdx.x;
  const size_t row0 = (size_t)bid * BM;

  const float alpha = alphap[0];
  const float* c2g = (const float*)(ws + WS_C2);
  float* partials = (float*)(ws + WS_PART);

  float c2r[4];
#pragma unroll
  for (int n = 0; n < 4; ++n) c2r[n] = c2g[w * 64 + n * 16 + l15];

  f32x4 acc[4][4];
#pragma unroll
  for (int m = 0; m < 4; ++m)
#pragma unroll
    for (int n = 0; n < 4; ++n) acc[m][n] = (f32x4){0.f, 0.f, 0.f, 0.f};

  // x staging thread mapping: thread handles (row r0, float4 col c0) and (r0+32, c0)
  const int r0 = t >> 4;
  const int c0 = t & 15;
  const int r1 = r0 + 32;
  const int slotc = c0 >> 1;
  const int withn = (c0 & 1) * 8;
  const uint32_t xoff0 = (uint32_t)r0 * 128u + (uint32_t)(((slotc ^ (r0 & 7)) << 4) + withn);
  const uint32_t xoff1 = (uint32_t)r1 * 128u + (uint32_t)(((slotc ^ (r1 & 7)) << 4) + withn);
  const float* xg0 = emb + (row0 + r0) * DEMB + c0 * 4;
  const float* xg1 = emb + (row0 + r1) * DEMB + c0 * 4;

  float x2a0 = 0.f, x2a1 = 0.f;

  // per-wave B fragment base: lane l's 16B; frag (ch,kk,n) at + ch*64KB + (kk*4+n)*1KB
  const uint8_t* fb = ws + WS_CB + (uint32_t)w * 8192u + (uint32_t)l * 16u;

  short8 bA[8], bB[8];

  // ---- prologue: emb[0],emb[1] regs; B[0] -> bA; stage A[0] ----
  float4 pa0 = *(const float4*)(xg0);
  float4 pa1 = *(const float4*)(xg1);
  float4 pb0 = *(const float4*)(xg0 + 64);
  float4 pb1 = *(const float4*)(xg1 + 64);
#pragma unroll
  for (int i = 0; i < 8; ++i) bA[i] = *(const short8*)(fb + (uint32_t)i * 1024u);
  {
    x2a0 += pa0.x * pa0.x + pa0.y * pa0.y + pa0.z * pa0.z + pa0.w * pa0.w;
    x2a1 += pa1.x * pa1.x + pa1.y * pa1.y + pa1.z * pa1.z + pa1.w * pa1.w;
    ushort4 u0, u1;
    u0.x = f2bf(pa0.x); u0.y = f2bf(pa0.y); u0.z = f2bf(pa0.z); u0.w = f2bf(pa0.w);
    u1.x = f2bf(pa1.x); u1.y = f2bf(pa1.y); u1.z = f2bf(pa1.z); u1.w = f2bf(pa1.w);
    *(ushort4*)(&Ab[0][0] + xoff0) = u0;
    *(ushort4*)(&Ab[0][0] + xoff1) = u1;
  }
  __syncthreads();

#define CHUNK_BODY(CH, BCUR, BNEXT, EP0, EP1, ES0, ES1)                      \
  {                                                                           \
    if ((CH) + 1 < NCHUNK) {                                                  \
      const uint8_t* srcn = fb + (uint32_t)((CH) + 1) * 65536u;               \
      _Pragma("unroll")                                                       \
      for (int i = 0; i < 8; ++i)                                             \
        BNEXT[i] = *(const short8*)(srcn + (uint32_t)i * 1024u);              \
    }                                                                         \
    if ((CH) + 2 < NCHUNK) {                                                  \
      EP0 = *(const float4*)(xg0 + ((CH) + 2) * 64);                          \
      EP1 = *(const float4*)(xg1 + ((CH) + 2) * 64);                          \
    }                                                                         \
    const uint8_t* xb = &Ab[(CH) & 1][0];                                     \
    short8 af[4][2];                                                          \
    _Pragma("unroll")                                                         \
    for (int kk = 0; kk < 2; ++kk) {                                          \
      const int slot = kk * 4 + lhi;                                          \
      const uint32_t fo =                                                     \
          (uint32_t)l15 * 128u + (uint32_t)((slot ^ (l15 & 7)) << 4);         \
      _Pragma("unroll")                                                       \
      for (int m = 0; m < 4; ++m)                                             \
        af[m][kk] = *(const short8*)(xb + fo + (uint32_t)m * 2048u);          \
    }                                                                         \
    __builtin_amdgcn_s_setprio(1);                                            \
    _Pragma("unroll")                                                         \
    for (int kk = 0; kk < 2; ++kk)                                            \
      _Pragma("unroll")                                                       \
      for (int m = 0; m < 4; ++m)                                             \
        _Pragma("unroll")                                                     \
        for (int n = 0; n < 4; ++n)                                           \
          acc[m][n] = __builtin_amdgcn_mfma_f32_16x16x32_bf16(                \
              af[m][kk], BCUR[kk * 4 + n], acc[m][n], 0, 0, 0);               \
    __builtin_amdgcn_s_setprio(0);                                            \
    if ((CH) + 1 < NCHUNK) {                                                  \
      float4 q0 = ES0, q1 = ES1;                                              \
      x2a0 += q0.x * q0.x + q0.y * q0.y + q0.z * q0.z + q0.w * q0.w;          \
      x2a1 += q1.x * q1.x + q1.y * q1.y + q1.z * q1.z + q1.w * q1.w;          \
      ushort4 u0, u1;                                                         \
      u0.x = f2bf(q0.x); u0.y = f2bf(q0.y); u0.z = f2bf(q0.z); u0.w = f2bf(q0.w); \
      u1.x = f2bf(q1.x); u1.y = f2bf(q1.y); u1.z = f2bf(q1.z); u1.w = f2bf(q1.w); \
      uint8_t* an = &Ab[((CH) + 1) & 1][0];                                   \
      *(ushort4*)(an + xoff0) = u0;                                           \
      *(ushort4*)(an + xoff1) = u1;                                           \
    }                                                                         \
    __syncthreads();                                                          \
  }

  // even CH: prefetch emb[CH+2] into pa, stage emb[CH+1] from pb; odd: swapped
  CHUNK_BODY(0, bA, bB, pa0, pa1, pb0, pb1)
  CHUNK_BODY(1, bB, bA, pb0, pb1, pa0, pa1)
  CHUNK_BODY(2, bA, bB, pa0, pa1, pb0, pb1)
  CHUNK_BODY(3, bB, bA, pb0, pb1, pa0, pa1)
  CHUNK_BODY(4, bA, bB, pa0, pa1, pb0, pb1)
  CHUNK_BODY(5, bB, bA, pb0, pb1, pa0, pa1)
  CHUNK_BODY(6, bA, bB, pa0, pa1, pb0, pb1)
  CHUNK_BODY(7, bB, bA, pb0, pb1, pa0, pa1)
#undef CHUNK_BODY

  // ---- epilogue: g = c2 - 2*s ; val_row = min + sum((g-M)e)/sum(e) + x2 ----
#pragma unroll
  for (int m = 1; m < 16; m <<= 1) {
    x2a0 += __shfl_xor(x2a0, m, 64);
    x2a1 += __shfl_xor(x2a1, m, 64);
  }
  if ((t & 15) == 0) {
    x2s[t >> 4] = x2a0;
    x2s[32 + (t >> 4)] = x2a1;
  }

  float rmin[4][4];
#pragma unroll
  for (int m = 0; m < 4; ++m)
#pragma unroll
    for (int i = 0; i < 4; ++i) {
      float mn = c2r[0] - 2.f * acc[m][0][i];
#pragma unroll
      for (int n = 1; n < 4; ++n) mn = fminf(mn, c2r[n] - 2.f * acc[m][n][i]);
      rmin[m][i] = mn;
    }
#pragma unroll
  for (int msk = 1; msk < 16; msk <<= 1)
#pragma unroll
    for (int m = 0; m < 4; ++m)
#pragma unroll
      for (int i = 0; i < 4; ++i)
        rmin[m][i] = fminf(rmin[m][i], __shfl_xor(rmin[m][i], msk, 64));
  if (l15 == 0) {
#pragma unroll
    for (int m = 0; m < 4; ++m)
#pragma unroll
      for (int i = 0; i < 4; ++i)
        redmin[w * 64 + m * 16 + lhi * 4 + i] = rmin[m][i];
  }
  __syncthreads();
  if (t < 64) {
    float mn = redmin[t];
#pragma unroll
    for (int w2 = 1; w2 < 8; ++w2) mn = fminf(mn, redmin[w2 * 64 + t]);
    gmin[t] = mn;
  }
  __syncthreads();
#pragma unroll
  for (int m = 0; m < 4; ++m) {
#pragma unroll
    for (int i = 0; i < 4; ++i) {
      const int row = m * 16 + lhi * 4 + i;
      const float M = gmin[row];
      float se = 0.f, sge = 0.f;
#pragma unroll
      for (int n = 0; n < 4; ++n) {
        const float g = c2r[n] - 2.f * acc[m][n][i];
        const float gm = g - M;
        const float e = __expf(-alpha * gm);
        se += e;
        sge += gm * e;
      }
#pragma unroll
      for (int msk = 1; msk < 16; msk <<= 1) {
        se += __shfl_xor(se, msk, 64);
        sge += __shfl_xor(sge, msk, 64);
      }
      if (l15 == 0) {
        redse[w * 64 + row] = se;
        redsge[w * 64 + row] = sge;
      }
    }
  }
  __syncthreads();
  if (t < 64) {
    float Se = 0.f, Sge = 0.f;
#pragma unroll
    for (int w2 = 0; w2 < 8; ++w2) {
      Se += redse[w2 * 64 + t];
      Sge += redsge[w2 * 64 + t];
    }
    vals[t] = gmin[t] + Sge / Se + x2s[t];
  }
  __syncthreads();
  if (t < 64) {
    float v = vals[t];
#pragma unroll
    for (int msk = 1; msk < 64; msk <<= 1) v += __shfl_xor(v, msk, 64);
    if (t == 0) partials[bid] = v;
  }
}

// ---------- final deterministic reduction ----------
__global__ __launch_bounds__(256) void final_kernel(const uint8_t* __restrict__ ws,
                                                    const float* __restrict__ lambdp,
                                                    float* __restrict__ out) {
  const float* partials = (const float*)(ws + WS_PART);
  const int t = threadIdx.x;
  float s = 0.f;
  for (int i = t; i < NBLK; i += 256) s += partials[i];
#pragma unroll
  for (int msk = 1; msk < 64; msk <<= 1) s += __shfl_xor(s, msk, 64);
  __shared__ float red[4];
  if ((t & 63) == 0) red[t >> 6] = s;
  __syncthreads();
  if (t == 0)
    out[0] = lambdp[0] * (red[0] + red[1] + red[2] + red[3]) * (1.0f / (float)NPTS);
}

extern "C" void kernel_launch(void* const* d_in, const int* in_sizes, int n_in,
                              void* d_out, int out_size, void* d_ws, size_t ws_size,
                              hipStream_t stream) {
  const float* emb = (const float*)d_in[0];
  const float* cent = (const float*)d_in[1];
  const float* alphap = (const float*)d_in[2];
  const float* lambdp = (const float*)d_in[3];
  float* out = (float*)d_out;
  uint8_t* ws = (uint8_t*)d_ws;

  prep_kernel<<<NCL, 128, 0, stream>>>(cent, ws);
  main_kernel<<<NBLK, NTHREADS, 0, stream>>>(emb, ws, alphap);
  final_kernel<<<1, 256, 0, stream>>>(ws, lambdp, out);
}

// Round 5
// 138.038 us; speedup vs baseline: 1.3173x; 1.0462x over previous
//
#include <hip/hip_runtime.h>
#include <stdint.h>

#define NPTS   131072
#define DEMB   512
#define NCL    512
#define BM     64
#define NCHUNK 8
#define NTHREADS 512
#define NBLK   (NPTS / BM)          // 2048

typedef __attribute__((ext_vector_type(4))) float f32x4;
typedef __attribute__((ext_vector_type(8))) short short8;

// ---- workspace layout (bytes) ----
// [0, 512KB)  : bf16 centroid fragments, per (chunk, wave, kk, n, lane):
//               each wave's (ch,kk,n) B-fragment is one contiguous 1KB wave-read.
// [512KB,+2KB): c2[k] = ||c_k||^2 (f32)
// [514KB,+8KB): per-block partial sums (f32)
#define WS_CB   0u
#define WS_C2   (512u * 1024u)
#define WS_PART (WS_C2 + 2048u)

static __device__ __forceinline__ unsigned short f2bf(float f) {
  union { float f; uint32_t u; } c{f};
  uint32_t r = c.u + 0x7FFFu + ((c.u >> 16) & 1u);   // round-to-nearest-even
  return (unsigned short)(r >> 16);
}

static __device__ __forceinline__ float sq4(f32x4 v) {
  return v[0] * v[0] + v[1] * v[1] + v[2] * v[2] + v[3] * v[3];
}
static __device__ __forceinline__ ushort4 cvt4(f32x4 v) {
  ushort4 u;
  u.x = f2bf(v[0]); u.y = f2bf(v[1]); u.z = f2bf(v[2]); u.w = f2bf(v[3]);
  return u;
}

// ---- pinned-schedule load/wait primitives (volatile asm keeps program order) ----
#define LOAD_B8(DST, BASE)                                                     \
  do {                                                                         \
    const uint8_t* _b0 = (const uint8_t*)(BASE);                               \
    const uint8_t* _b1 = _b0 + 4096;                                           \
    asm volatile("global_load_dwordx4 %0, %8, off\n\t"                         \
                 "global_load_dwordx4 %1, %8, off offset:1024\n\t"             \
                 "global_load_dwordx4 %2, %8, off offset:2048\n\t"             \
                 "global_load_dwordx4 %3, %8, off offset:3072\n\t"             \
                 "global_load_dwordx4 %4, %9, off\n\t"                         \
                 "global_load_dwordx4 %5, %9, off offset:1024\n\t"             \
                 "global_load_dwordx4 %6, %9, off offset:2048\n\t"             \
                 "global_load_dwordx4 %7, %9, off offset:3072"                 \
                 : "=&v"(DST[0]), "=&v"(DST[1]), "=&v"(DST[2]), "=&v"(DST[3]), \
                   "=&v"(DST[4]), "=&v"(DST[5]), "=&v"(DST[6]), "=&v"(DST[7])  \
                 : "v"(_b0), "v"(_b1)                                          \
                 : "memory");                                                  \
  } while (0)

#define LOAD_E2(D0, D1, P0, P1)                                                \
  asm volatile("global_load_dwordx4 %0, %2, off\n\t"                           \
               "global_load_dwordx4 %1, %3, off"                               \
               : "=&v"(D0), "=&v"(D1)                                          \
               : "v"(P0), "v"(P1)                                              \
               : "memory")

#define WAITV(N)                                                               \
  do {                                                                         \
    asm volatile("s_waitcnt vmcnt(" #N ")" ::: "memory");                      \
    __builtin_amdgcn_sched_barrier(0);                                         \
  } while (0)

#define BAR()                                                                  \
  do {                                                                         \
    asm volatile("s_waitcnt lgkmcnt(0)" ::: "memory");                         \
    __builtin_amdgcn_s_barrier();                                              \
  } while (0)

// ---------- prep: c2 + bf16 centroid fragments in register-load layout ----------
__global__ __launch_bounds__(128) void prep_kernel(const float* __restrict__ cent,
                                                   uint8_t* __restrict__ ws) {
  const int k = blockIdx.x;
  const int t = threadIdx.x;
  float4 v = ((const float4*)(cent + (size_t)k * DEMB))[t];
  float sq = v.x * v.x + v.y * v.y + v.z * v.z + v.w * v.w;
#pragma unroll
  for (int m = 1; m < 64; m <<= 1) sq += __shfl_xor(sq, m, 64);
  __shared__ float red[2];
  if ((t & 63) == 0) red[t >> 6] = sq;
  __syncthreads();
  if (t == 0) ((float*)(ws + WS_C2))[k] = red[0] + red[1];

  ushort4 b;
  b.x = f2bf(v.x); b.y = f2bf(v.y); b.z = f2bf(v.z); b.w = f2bf(v.w);
  const int d = t * 4;
  const int ch = d >> 6;
  const int dd = d & 63;
  const int slot = dd >> 3;            // 0..7
  const int kk = slot >> 2;            // 0..1
  const int lhi = slot & 3;            // 0..3
  const int w = k >> 6;
  const int kc = k & 63;
  const int n = kc >> 4;
  const int l15 = kc & 15;
  const int lane = lhi * 16 + l15;
  const uint32_t off =
      ((((uint32_t)(ch * 8 + w) * 2u + (uint32_t)kk) * 4u + (uint32_t)n) * 64u +
       (uint32_t)lane) * 16u + (uint32_t)(dd & 7) * 2u;
  *(ushort4*)(ws + WS_CB + off) = b;
}

// ---------- fused GEMM + softmin epilogue: pinned counted-vmcnt pipeline ----------
__global__ __launch_bounds__(NTHREADS, 2) void main_kernel(
    const float* __restrict__ emb, const uint8_t* __restrict__ ws,
    const float* __restrict__ alphap) {
  __shared__ uint8_t Ab[2][8192];      // A tile dbuf [64 rows][64 d] bf16, XOR-swizzled
  __shared__ float redmin[512];
  __shared__ float redse[512];
  __shared__ float redsge[512];
  __shared__ float gmin[64];
  __shared__ float x2s[64];
  __shared__ float vals[64];

  const int t = threadIdx.x;
  const int w = t >> 6;                // wave 0..7 -> clusters [64w, 64w+64)
  const int l = t & 63;
  const int l15 = l & 15;
  const int lhi = l >> 4;              // 0..3
  const int bid = blockIdx.x;
  const size_t row0 = (size_t)bid * BM;

  float* partials = (float*)(ws + WS_PART);

  f32x4 acc[4][4];
#pragma unroll
  for (int m = 0; m < 4; ++m)
#pragma unroll
    for (int n = 0; n < 4; ++n) acc[m][n] = (f32x4){0.f, 0.f, 0.f, 0.f};

  // x staging thread mapping: thread handles (row r0, float4 col c0) and (r0+32, c0)
  const int r0 = t >> 4;
  const int c0 = t & 15;
  const int r1 = r0 + 32;
  const int slotc = c0 >> 1;
  const int withn = (c0 & 1) * 8;
  const uint32_t xoff0 = (uint32_t)r0 * 128u + (uint32_t)(((slotc ^ (r0 & 7)) << 4) + withn);
  const uint32_t xoff1 = (uint32_t)r1 * 128u + (uint32_t)(((slotc ^ (r1 & 7)) << 4) + withn);
  const float* xg0 = emb + (row0 + r0) * DEMB + c0 * 4;
  const float* xg1 = emb + (row0 + r1) * DEMB + c0 * 4;

  float x2a0 = 0.f, x2a1 = 0.f;

  // per-wave B fragment base: lane l's 16B; frag (ch,kk,n) at + ch*64KB + (kk*4+n)*1KB
  const uint8_t* fb = ws + WS_CB + (uint32_t)w * 8192u + (uint32_t)l * 16u;

  short8 bA[8], bB[8];
  f32x4 pe0, pe1, po0, po1;

  // ---- prologue: E[0]->pe, B[0]->bA, E[1]->po; stage A[0] ----
  LOAD_E2(pe0, pe1, xg0, xg1);
  LOAD_B8(bA, fb);
  LOAD_E2(po0, po1, xg0 + 64, xg1 + 64);
  WAITV(10);                            // E[0] landed; B[0] + E[1] stay in flight
  x2a0 += sq4(pe0);
  x2a1 += sq4(pe1);
  *(ushort4*)(&Ab[0][0] + xoff0) = cvt4(pe0);
  *(ushort4*)(&Ab[0][0] + xoff1) = cvt4(pe1);
  BAR();

#define CHUNK_BODY(CH, BCUR, BNEXT, PL0, PL1, PS0, PS1, VN)                    \
  {                                                                            \
    if ((CH) + 1 < NCHUNK)                                                     \
      LOAD_B8(BNEXT, fb + (uint32_t)((CH) + 1) * 65536u);                      \
    if ((CH) + 2 < NCHUNK)                                                     \
      LOAD_E2(PL0, PL1, xg0 + ((CH) + 2) * 64, xg1 + ((CH) + 2) * 64);         \
    const uint8_t* xb = &Ab[(CH) & 1][0];                                      \
    short8 af[4][2];                                                           \
    _Pragma("unroll")                                                          \
    for (int kk = 0; kk < 2; ++kk) {                                           \
      const int slot = kk * 4 + lhi;                                           \
      const uint32_t fo =                                                      \
          (uint32_t)l15 * 128u + (uint32_t)((slot ^ (l15 & 7)) << 4);          \
      _Pragma("unroll")                                                        \
      for (int m = 0; m < 4; ++m)                                              \
        af[m][kk] = *(const short8*)(xb + fo + (uint32_t)m * 2048u);           \
    }                                                                          \
    WAITV(VN);                                                                 \
    __builtin_amdgcn_s_setprio(1);                                             \
    _Pragma("unroll")                                                          \
    for (int kk = 0; kk < 2; ++kk)                                             \
      _Pragma("unroll")                                                        \
      for (int m = 0; m < 4; ++m)                                              \
        _Pragma("unroll")                                                      \
        for (int n = 0; n < 4; ++n)                                            \
          acc[m][n] = __builtin_amdgcn_mfma_f32_16x16x32_bf16(                 \
              af[m][kk], BCUR[kk * 4 + n], acc[m][n], 0, 0, 0);                \
    __builtin_amdgcn_s_setprio(0);                                             \
    if ((CH) + 1 < NCHUNK) {                                                   \
      x2a0 += sq4(PS0);                                                        \
      x2a1 += sq4(PS1);                                                        \
      uint8_t* an = &Ab[((CH) + 1) & 1][0];                                    \
      *(ushort4*)(an + xoff0) = cvt4(PS0);                                     \
      *(ushort4*)(an + xoff1) = cvt4(PS1);                                     \
    }                                                                          \
    BAR();                                                                     \
  }

  CHUNK_BODY(0, bA, bB, pe0, pe1, po0, po1, 10)
  CHUNK_BODY(1, bB, bA, po0, po1, pe0, pe1, 10)
  CHUNK_BODY(2, bA, bB, pe0, pe1, po0, po1, 10)
  CHUNK_BODY(3, bB, bA, po0, po1, pe0, pe1, 10)
  CHUNK_BODY(4, bA, bB, pe0, pe1, po0, po1, 10)
  CHUNK_BODY(5, bB, bA, po0, po1, pe0, pe1, 10)
  CHUNK_BODY(6, bA, bB, pe0, pe1, po0, po1, 8)
  CHUNK_BODY(7, bB, bA, po0, po1, pe0, pe1, 0)
#undef CHUNK_BODY

  // ---- epilogue (all manual vmem drained at body 7's vmcnt(0)) ----
  const float alpha = alphap[0];
  const float* c2g = (const float*)(ws + WS_C2);
  float c2r[4];
  {
    const float* c2p = c2g + w * 64 + l15;
    asm volatile("global_load_dword %0, %4, off\n\t"
                 "global_load_dword %1, %4, off offset:64\n\t"
                 "global_load_dword %2, %4, off offset:128\n\t"
                 "global_load_dword %3, %4, off offset:192"
                 : "=&v"(c2r[0]), "=&v"(c2r[1]), "=&v"(c2r[2]), "=&v"(c2r[3])
                 : "v"(c2p)
                 : "memory");
    asm volatile("s_waitcnt vmcnt(0)" ::: "memory");
    __builtin_amdgcn_sched_barrier(0);
  }

#pragma unroll
  for (int m = 1; m < 16; m <<= 1) {
    x2a0 += __shfl_xor(x2a0, m, 64);
    x2a1 += __shfl_xor(x2a1, m, 64);
  }
  if ((t & 15) == 0) {
    x2s[t >> 4] = x2a0;
    x2s[32 + (t >> 4)] = x2a1;
  }

  float rmin[4][4];
#pragma unroll
  for (int m = 0; m < 4; ++m)
#pragma unroll
    for (int i = 0; i < 4; ++i) {
      float mn = c2r[0] - 2.f * acc[m][0][i];
#pragma unroll
      for (int n = 1; n < 4; ++n) mn = fminf(mn, c2r[n] - 2.f * acc[m][n][i]);
      rmin[m][i] = mn;
    }
#pragma unroll
  for (int msk = 1; msk < 16; msk <<= 1)
#pragma unroll
    for (int m = 0; m < 4; ++m)
#pragma unroll
      for (int i = 0; i < 4; ++i)
        rmin[m][i] = fminf(rmin[m][i], __shfl_xor(rmin[m][i], msk, 64));
  if (l15 == 0) {
#pragma unroll
    for (int m = 0; m < 4; ++m)
#pragma unroll
      for (int i = 0; i < 4; ++i)
        redmin[w * 64 + m * 16 + lhi * 4 + i] = rmin[m][i];
  }
  __syncthreads();
  if (t < 64) {
    float mn = redmin[t];
#pragma unroll
    for (int w2 = 1; w2 < 8; ++w2) mn = fminf(mn, redmin[w2 * 64 + t]);
    gmin[t] = mn;
  }
  __syncthreads();
#pragma unroll
  for (int m = 0; m < 4; ++m) {
#pragma unroll
    for (int i = 0; i < 4; ++i) {
      const int row = m * 16 + lhi * 4 + i;
      const float M = gmin[row];
      float se = 0.f, sge = 0.f;
#pragma unroll
      for (int n = 0; n < 4; ++n) {
        const float g = c2r[n] - 2.f * acc[m][n][i];
        const float gm = g - M;
        const float e = __expf(-alpha * gm);
        se += e;
        sge += gm * e;
      }
#pragma unroll
      for (int msk = 1; msk < 16; msk <<= 1) {
        se += __shfl_xor(se, msk, 64);
        sge += __shfl_xor(sge, msk, 64);
      }
      if (l15 == 0) {
        redse[w * 64 + row] = se;
        redsge[w * 64 + row] = sge;
      }
    }
  }
  __syncthreads();
  if (t < 64) {
    float Se = 0.f, Sge = 0.f;
#pragma unroll
    for (int w2 = 0; w2 < 8; ++w2) {
      Se += redse[w2 * 64 + t];
      Sge += redsge[w2 * 64 + t];
    }
    vals[t] = gmin[t] + Sge / Se + x2s[t];
  }
  __syncthreads();
  if (t < 64) {
    float v = vals[t];
#pragma unroll
    for (int msk = 1; msk < 64; msk <<= 1) v += __shfl_xor(v, msk, 64);
    if (t == 0) partials[bid] = v;
  }
}

// ---------- final deterministic reduction ----------
__global__ __launch_bounds__(256) void final_kernel(const uint8_t* __restrict__ ws,
                                                    const float* __restrict__ lambdp,
                                                    float* __restrict__ out) {
  const float* partials = (const float*)(ws + WS_PART);
  const int t = threadIdx.x;
  float s = 0.f;
  for (int i = t; i < NBLK; i += 256) s += partials[i];
#pragma unroll
  for (int msk = 1; msk < 64; msk <<= 1) s += __shfl_xor(s, msk, 64);
  __shared__ float red[4];
  if ((t & 63) == 0) red[t >> 6] = s;
  __syncthreads();
  if (t == 0)
    out[0] = lambdp[0] * (red[0] + red[1] + red[2] + red[3]) * (1.0f / (float)NPTS);
}

extern "C" void kernel_launch(void* const* d_in, const int* in_sizes, int n_in,
                              void* d_out, int out_size, void* d_ws, size_t ws_size,
                              hipStream_t stream) {
  const float* emb = (const float*)d_in[0];
  const float* cent = (const float*)d_in[1];
  const float* alphap = (const float*)d_in[2];
  const float* lambdp = (const float*)d_in[3];
  float* out = (float*)d_out;
  uint8_t* ws = (uint8_t*)d_ws;

  prep_kernel<<<NCL, 128, 0, stream>>>(cent, ws);
  main_kernel<<<NBLK, NTHREADS, 0, stream>>>(emb, ws, alphap);
  final_kernel<<<1, 256, 0, stream>>>(ws, lambdp, out);
}

// Round 7
// 125.937 us; speedup vs baseline: 1.4438x; 1.0961x over previous
//
#include <hip/hip_runtime.h>
#include <stdint.h>

#define NPTS   131072
#define DEMB   512
#define NCL    512
#define BM     128
#define NCHUNK 8
#define NTHREADS 512
#define NBLK   (NPTS / BM)          // 1024

typedef __attribute__((ext_vector_type(4))) float f32x4;
typedef __attribute__((ext_vector_type(8))) short short8;

// ---- workspace layout (bytes) ----
// [0, 512KB)  : bf16 centroid fragments, per (chunk, wave, kk, n, lane):
//               each wave's (ch,kk,n) B-fragment is one contiguous 1KB wave-read.
// [512KB,+2KB): c2[k] = ||c_k||^2 (f32)
// [514KB,+8KB): per-block partial sums (f32)
#define WS_CB   0u
#define WS_C2   (512u * 1024u)
#define WS_PART (WS_C2 + 2048u)

static __device__ __forceinline__ unsigned short f2bf(float f) {
  union { float f; uint32_t u; } c{f};
  uint32_t r = c.u + 0x7FFFu + ((c.u >> 16) & 1u);   // round-to-nearest-even
  return (unsigned short)(r >> 16);
}

static __device__ __forceinline__ float sq4(f32x4 v) {
  return v[0] * v[0] + v[1] * v[1] + v[2] * v[2] + v[3] * v[3];
}
static __device__ __forceinline__ ushort4 cvt4(f32x4 v) {
  ushort4 u;
  u.x = f2bf(v[0]); u.y = f2bf(v[1]); u.z = f2bf(v[2]); u.w = f2bf(v[3]);
  return u;
}

// ---- pinned-schedule load/wait primitives (volatile asm keeps program order) ----
#define LOAD_B8(DST, BASE)                                                     \
  do {                                                                         \
    const uint8_t* _b0 = (const uint8_t*)(BASE);                               \
    const uint8_t* _b1 = _b0 + 4096;                                           \
    asm volatile("global_load_dwordx4 %0, %8, off\n\t"                         \
                 "global_load_dwordx4 %1, %8, off offset:1024\n\t"             \
                 "global_load_dwordx4 %2, %8, off offset:2048\n\t"             \
                 "global_load_dwordx4 %3, %8, off offset:3072\n\t"             \
                 "global_load_dwordx4 %4, %9, off\n\t"                         \
                 "global_load_dwordx4 %5, %9, off offset:1024\n\t"             \
                 "global_load_dwordx4 %6, %9, off offset:2048\n\t"             \
                 "global_load_dwordx4 %7, %9, off offset:3072"                 \
                 : "=&v"(DST[0]), "=&v"(DST[1]), "=&v"(DST[2]), "=&v"(DST[3]), \
                   "=&v"(DST[4]), "=&v"(DST[5]), "=&v"(DST[6]), "=&v"(DST[7])  \
                 : "v"(_b0), "v"(_b1)                                          \
                 : "memory");                                                  \
  } while (0)

#define LOAD_E4(D, P)                                                          \
  asm volatile("global_load_dwordx4 %0, %4, off\n\t"                           \
               "global_load_dwordx4 %1, %4, off offset:16\n\t"                 \
               "global_load_dwordx4 %2, %4, off offset:32\n\t"                 \
               "global_load_dwordx4 %3, %4, off offset:48"                     \
               : "=&v"(D[0]), "=&v"(D[1]), "=&v"(D[2]), "=&v"(D[3])            \
               : "v"(P)                                                        \
               : "memory")

#define WAITV(N)                                                               \
  do {                                                                         \
    asm volatile("s_waitcnt vmcnt(" #N ")" ::: "memory");                      \
    __builtin_amdgcn_sched_barrier(0);                                         \
  } while (0)

#define BAR()                                                                  \
  do {                                                                         \
    asm volatile("s_waitcnt lgkmcnt(0)" ::: "memory");                         \
    __builtin_amdgcn_s_barrier();                                              \
  } while (0)

// ---------- prep: c2 + bf16 centroid fragments in register-load layout ----------
__global__ __launch_bounds__(128) void prep_kernel(const float* __restrict__ cent,
                                                   uint8_t* __restrict__ ws) {
  const int k = blockIdx.x;
  const int t = threadIdx.x;
  float4 v = ((const float4*)(cent + (size_t)k * DEMB))[t];
  float sq = v.x * v.x + v.y * v.y + v.z * v.z + v.w * v.w;
#pragma unroll
  for (int m = 1; m < 64; m <<= 1) sq += __shfl_xor(sq, m, 64);
  __shared__ float red[2];
  if ((t & 63) == 0) red[t >> 6] = sq;
  __syncthreads();
  if (t == 0) ((float*)(ws + WS_C2))[k] = red[0] + red[1];

  ushort4 b;
  b.x = f2bf(v.x); b.y = f2bf(v.y); b.z = f2bf(v.z); b.w = f2bf(v.w);
  const int d = t * 4;
  const int ch = d >> 6;
  const int dd = d & 63;
  const int slot = dd >> 3;            // 0..7
  const int kk = slot >> 2;            // 0..1
  const int lhi = slot & 3;            // 0..3
  const int w = k >> 6;
  const int kc = k & 63;
  const int n = kc >> 4;
  const int l15 = kc & 15;
  const int lane = lhi * 16 + l15;
  const uint32_t off =
      ((((uint32_t)(ch * 8 + w) * 2u + (uint32_t)kk) * 4u + (uint32_t)n) * 64u +
       (uint32_t)lane) * 16u + (uint32_t)(dd & 7) * 2u;
  *(ushort4*)(ws + WS_CB + off) = b;
}

// ---------- fused GEMM + softmin epilogue: BM=128, pinned counted-vmcnt ----------
__global__ __launch_bounds__(NTHREADS, 2) void main_kernel(
    const float* __restrict__ emb, const uint8_t* __restrict__ ws,
    const float* __restrict__ alphap) {
  __shared__ uint8_t Ab[2][16384];     // A tile dbuf [128 rows][64 d] bf16, XOR-swizzled
  __shared__ float redmin[1024];       // [8 waves][128 rows]
  __shared__ float redse[1024];
  __shared__ float redsge[1024];
  __shared__ float gmin[128];
  __shared__ float x2s[128];

  const int t = threadIdx.x;
  const int w = t >> 6;                // wave 0..7 -> clusters [64w, 64w+64)
  const int l = t & 63;
  const int l15 = l & 15;
  const int lhi = l >> 4;              // 0..3
  const int bid = blockIdx.x;
  const size_t row0 = (size_t)bid * BM;

  float* partials = (float*)(ws + WS_PART);

  f32x4 acc[8][4];
#pragma unroll
  for (int m = 0; m < 8; ++m)
#pragma unroll
    for (int n = 0; n < 4; ++n) acc[m][n] = (f32x4){0.f, 0.f, 0.f, 0.f};

  // x staging: thread owns 64B of one row: row r = t>>2, float cols [q*16, q*16+16)
  const int r = t >> 2;
  const int q = t & 3;
  const float* xge = emb + (row0 + r) * DEMB + q * 16;
  uint32_t xoffs[4];
#pragma unroll
  for (int j = 0; j < 4; ++j)
    xoffs[j] = (uint32_t)r * 128u +
               (uint32_t)((((2 * q + (j >> 1)) ^ (r & 7)) << 4) + (j & 1) * 8);

  float x2a = 0.f;

  // per-wave B fragment base: lane l's 16B; frag (ch,kk,n) at + ch*64KB + (kk*4+n)*1KB
  const uint8_t* fb = ws + WS_CB + (uint32_t)w * 8192u + (uint32_t)l * 16u;

  short8 bA[8], bB[8];
  f32x4 ev[4];

  // ---- prologue: E[0] first, then B[0]; vmcnt(8) -> E[0] landed, B[0] in flight
  LOAD_E4(ev, xge);
  LOAD_B8(bA, fb);
  WAITV(8);
#pragma unroll
  for (int j = 0; j < 4; ++j) {
    x2a += sq4(ev[j]);
    *(ushort4*)(&Ab[0][0] + xoffs[j]) = cvt4(ev[j]);
  }
  BAR();

// E-first issue order. Steady state: body top has 8 outstanding (B[cur]).
// After issuing E[ch+1](4)+B[ch+1](8): 20. Pre-MFMA vmcnt(12) retires exactly
// B[cur]; post-MFMA vmcnt(8) retires exactly E[ch+1] before staging reads ev.
#define CHUNK_BODY(CH, BCUR, BNEXT, VN1)                                       \
  {                                                                            \
    if ((CH) + 1 < NCHUNK) {                                                   \
      LOAD_E4(ev, xge + ((CH) + 1) * 64);                                      \
      LOAD_B8(BNEXT, fb + (uint32_t)((CH) + 1) * 65536u);                      \
    }                                                                          \
    const uint8_t* xb = &Ab[(CH) & 1][0];                                      \
    WAITV(VN1);                                                                \
    __builtin_amdgcn_s_setprio(1);                                             \
    _Pragma("unroll")                                                          \
    for (int kk = 0; kk < 2; ++kk) {                                           \
      const int slot = kk * 4 + lhi;                                           \
      const uint32_t fo =                                                      \
          (uint32_t)l15 * 128u + (uint32_t)((slot ^ (l15 & 7)) << 4);          \
      _Pragma("unroll")                                                        \
      for (int mh = 0; mh < 2; ++mh) {                                         \
        short8 af[4];                                                          \
        _Pragma("unroll")                                                      \
        for (int mm = 0; mm < 4; ++mm)                                         \
          af[mm] =                                                             \
              *(const short8*)(xb + fo + (uint32_t)(mh * 4 + mm) * 2048u);     \
        _Pragma("unroll")                                                      \
        for (int mm = 0; mm < 4; ++mm)                                         \
          _Pragma("unroll")                                                    \
          for (int n = 0; n < 4; ++n)                                          \
            acc[mh * 4 + mm][n] = __builtin_amdgcn_mfma_f32_16x16x32_bf16(     \
                af[mm], BCUR[kk * 4 + n], acc[mh * 4 + mm][n], 0, 0, 0);       \
      }                                                                        \
    }                                                                          \
    __builtin_amdgcn_s_setprio(0);                                             \
    if ((CH) + 1 < NCHUNK) {                                                   \
      WAITV(8);                                                                \
      uint8_t* an = &Ab[((CH) + 1) & 1][0];                                    \
      _Pragma("unroll")                                                        \
      for (int j = 0; j < 4; ++j) {                                            \
        x2a += sq4(ev[j]);                                                     \
        *(ushort4*)(an + xoffs[j]) = cvt4(ev[j]);                              \
      }                                                                        \
    }                                                                          \
    BAR();                                                                     \
  }

  CHUNK_BODY(0, bA, bB, 12)
  CHUNK_BODY(1, bB, bA, 12)
  CHUNK_BODY(2, bA, bB, 12)
  CHUNK_BODY(3, bB, bA, 12)
  CHUNK_BODY(4, bA, bB, 12)
  CHUNK_BODY(5, bB, bA, 12)
  CHUNK_BODY(6, bA, bB, 12)
  CHUNK_BODY(7, bB, bA, 0)
#undef CHUNK_BODY

  // ---- epilogue: g = c2 - 2*s ; val_row = min + sum((g-M)e)/sum(e) + x2 ----
  const float alpha = alphap[0];
  float c2r[4];
  {
    const float* c2p = (const float*)(ws + WS_C2) + w * 64 + l15;
    asm volatile("global_load_dword %0, %4, off\n\t"
                 "global_load_dword %1, %4, off offset:64\n\t"
                 "global_load_dword %2, %4, off offset:128\n\t"
                 "global_load_dword %3, %4, off offset:192"
                 : "=&v"(c2r[0]), "=&v"(c2r[1]), "=&v"(c2r[2]), "=&v"(c2r[3])
                 : "v"(c2p)
                 : "memory");
    asm volatile("s_waitcnt vmcnt(0)" ::: "memory");
    __builtin_amdgcn_sched_barrier(0);
  }

  // per-row x2: 4 threads per row (lanes 4k..4k+3)
  x2a += __shfl_xor(x2a, 1, 64);
  x2a += __shfl_xor(x2a, 2, 64);
  if ((l & 3) == 0) x2s[r] = x2a;     // one writer per row

  float rmin[8][4];
#pragma unroll
  for (int m = 0; m < 8; ++m)
#pragma unroll
    for (int i = 0; i < 4; ++i) {
      float mn = c2r[0] - 2.f * acc[m][0][i];
#pragma unroll
      for (int n = 1; n < 4; ++n) mn = fminf(mn, c2r[n] - 2.f * acc[m][n][i]);
      rmin[m][i] = mn;
    }
#pragma unroll
  for (int msk = 1; msk < 16; msk <<= 1)
#pragma unroll
    for (int m = 0; m < 8; ++m)
#pragma unroll
      for (int i = 0; i < 4; ++i)
        rmin[m][i] = fminf(rmin[m][i], __shfl_xor(rmin[m][i], msk, 64));
  if (l15 == 0) {
#pragma unroll
    for (int m = 0; m < 8; ++m)
#pragma unroll
      for (int i = 0; i < 4; ++i)
        redmin[w * 128 + m * 16 + lhi * 4 + i] = rmin[m][i];
  }
  __syncthreads();
  if (t < 128) {
    float mn = redmin[t];
#pragma unroll
    for (int w2 = 1; w2 < 8; ++w2) mn = fminf(mn, redmin[w2 * 128 + t]);
    gmin[t] = mn;
  }
  __syncthreads();
#pragma unroll
  for (int m = 0; m < 8; ++m) {
#pragma unroll
    for (int i = 0; i < 4; ++i) {
      const int row = m * 16 + lhi * 4 + i;
      const float M = gmin[row];
      float se = 0.f, sge = 0.f;
#pragma unroll
      for (int n = 0; n < 4; ++n) {
        const float g = c2r[n] - 2.f * acc[m][n][i];
        const float gm = g - M;
        const float e = __expf(-alpha * gm);
        se += e;
        sge += gm * e;
      }
#pragma unroll
      for (int msk = 1; msk < 16; msk <<= 1) {
        se += __shfl_xor(se, msk, 64);
        sge += __shfl_xor(sge, msk, 64);
      }
      if (l15 == 0) {
        redse[w * 128 + row] = se;
        redsge[w * 128 + row] = sge;
      }
    }
  }
  __syncthreads();
  if (t < 128) {
    float Se = 0.f, Sge = 0.f;
#pragma unroll
    for (int w2 = 0; w2 < 8; ++w2) {
      Se += redse[w2 * 128 + t];
      Sge += redsge[w2 * 128 + t];
    }
    float v = gmin[t] + Sge / Se + x2s[t];
#pragma unroll
    for (int msk = 1; msk < 64; msk <<= 1) v += __shfl_xor(v, msk, 64);
    if ((t & 63) == 0) redmin[t >> 6] = v;
  }
  __syncthreads();
  if (t == 0) partials[bid] = redmin[0] + redmin[1];
}

// ---------- final deterministic reduction ----------
__global__ __launch_bounds__(256) void final_kernel(const uint8_t* __restrict__ ws,
                                                    const float* __restrict__ lambdp,
                                                    float* __restrict__ out) {
  const float* partials = (const float*)(ws + WS_PART);
  const int t = threadIdx.x;
  float s = 0.f;
  for (int i = t; i < NBLK; i += 256) s += partials[i];
#pragma unroll
  for (int msk = 1; msk < 64; msk <<= 1) s += __shfl_xor(s, msk, 64);
  __shared__ float red[4];
  if ((t & 63) == 0) red[t >> 6] = s;
  __syncthreads();
  if (t == 0)
    out[0] = lambdp[0] * (red[0] + red[1] + red[2] + red[3]) * (1.0f / (float)NPTS);
}

extern "C" void kernel_launch(void* const* d_in, const int* in_sizes, int n_in,
                              void* d_out, int out_size, void* d_ws, size_t ws_size,
                              hipStream_t stream) {
  const float* emb = (const float*)d_in[0];
  const float* cent = (const float*)d_in[1];
  const float* alphap = (const float*)d_in[2];
  const float* lambdp = (const float*)d_in[3];
  float* out = (float*)d_out;
  uint8_t* ws = (uint8_t*)d_ws;

  prep_kernel<<<NCL, 128, 0, stream>>>(cent, ws);
  main_kernel<<<NBLK, NTHREADS, 0, stream>>>(emb, ws, alphap);
  final_kernel<<<1, 256, 0, stream>>>(ws, lambdp, out);
}